// Round 21
// baseline (241.992 us; speedup 1.0000x reference)
//
#include <hip/hip_runtime.h>
#include <math.h>

#define NN 11
#define RR 8192               // B*L positions
#define DD 1024
#define EPSV 1e-5f
#define PREP_TPB 256

// ---- ws layout (floats) ----
// wvec  : [22][1024] f32   @ 0
// scal  : [22][2]    f32   @ 22528 (padded to 64)
// wfrag : [32][2][64][8] bf16 @ 22592
#define OFF_SCAL 22528
#define OFF_WFRAG 22592

typedef __attribute__((ext_vector_type(8))) short short8;
typedef __attribute__((ext_vector_type(4))) float f32x4;

__device__ __forceinline__ float wave_reduce(float v) {
#pragma unroll
  for (int o = 32; o > 0; o >>= 1) v += __shfl_xor(v, o, 64);
  return v;
}

__device__ __forceinline__ unsigned cvtpk(float lo, float hi) {
  unsigned r;
  asm("v_cvt_pk_bf16_f32 %0, %1, %2" : "=v"(r) : "v"(lo), "v"(hi));
  return r;   // low16=bf16(lo), high16=bf16(hi); RTNE
}

__device__ __forceinline__ float b2f(unsigned short s) {
  return __uint_as_float(((unsigned)s) << 16);
}

__global__ __launch_bounds__(PREP_TPB) void prep_kernel(
    const float* __restrict__ aq, const float* __restrict__ ag, const float* __restrict__ ab,
    const float* __restrict__ mq, const float* __restrict__ mg, const float* __restrict__ mb,
    float* __restrict__ wvec, float* __restrict__ scal)
{
  const int j = blockIdx.x;              // 0..21
  const float *q, *g, *bt;
  if (j < NN) { q = aq + (size_t)j*DD;      g = ag + (size_t)j*DD;      bt = ab + (size_t)j*DD; }
  else        { q = mq + (size_t)(j-NN)*DD; g = mg + (size_t)(j-NN)*DD; bt = mb + (size_t)(j-NN)*DD; }
  const int t = threadIdx.x;
  float sqg = 0.f, sqb = 0.f;
  for (int d = t; d < DD; d += PREP_TPB) {
    float qq = q[d];
    float w  = qq * g[d];
    wvec[(size_t)j*DD + d] = w;
    sqg += w;
    sqb += qq * bt[d];
  }
  sqg = wave_reduce(sqg);
  sqb = wave_reduce(sqb);
  __shared__ float red[2][PREP_TPB/64];
  const int lane = t & 63, wid = t >> 6;
  if (lane == 0) { red[0][wid] = sqg; red[1][wid] = sqb; }
  __syncthreads();
  if (t == 0) {
    float a = 0.f, b2 = 0.f;
    for (int w = 0; w < PREP_TPB/64; ++w) { a += red[0][w]; b2 += red[1][w]; }
    scal[2*j]   = a;
    scal[2*j+1] = b2;
  }
}

// pack B fragments: wfrag[kstep][c][lane][e] = bf16(wvec[j][k]), j=c*16+(lane&15),
// k=kstep*32+(lane>>4)*8+e. j==22 -> 1.0 (row-sum rides the MFMA); other j>=22 -> 0.
__global__ __launch_bounds__(256) void prep2_kernel(
    const float* __restrict__ wvec, short* __restrict__ wfrag)
{
  const int kstep = blockIdx.x;          // 0..31
  const int t = threadIdx.x;
#pragma unroll
  for (int q = 0; q < 4; ++q) {
    const int idx  = t*4 + q;            // 0..1023
    const int c    = idx >> 9;
    const int lane = (idx >> 3) & 63;
    const int e    = idx & 7;
    const int k    = kstep*32 + (lane >> 4)*8 + e;
    const int j    = c*16 + (lane & 15);
    float v = (j < 22) ? wvec[(size_t)j*DD + k] : (j == 22 ? 1.0f : 0.f);
    unsigned u = __float_as_uint(v);
    u = (u + 0x7FFFu + ((u >> 16) & 1u)) >> 16;
    wfrag[(size_t)kstep*1024 + idx] = (short)u;
  }
}

// Fused, wave-specialized: block = ONE position, 4 waves; wave c owns K-chunk
// c. Stage wave-private (no barrier), MFMA wave-private, partials accumulated
// via LDS atomicAdd (no reduce phase), 3 barriers total, ~24.6 KB LDS ->
// 6 blocks/CU. Combine re-reads the thread's own wave chunk (low VGPR).
__global__ __launch_bounds__(256) void fused_kernel(
    const float* __restrict__ streams, const short* __restrict__ wfrag,
    const float* __restrict__ scal, float* __restrict__ out)
{
  __shared__ __align__(16) short xt[4*11*256];   // 22528 B: 4 wave-private chunks
  __shared__ float fl[11*36];                    // atomically-accumulated partials
  __shared__ float Cs[11][12];                   // final coeffs (zero-padded)

  const int p  = blockIdx.x;
  const int t  = threadIdx.x;
  const int l  = t & 63;
  const int wv = t >> 6;                 // wave = K-chunk
  const int lr = l & 15, g = l >> 4;

  // ---- zero the accumulator region (ALL 396 entries; 256-thread block) ----
  for (int s = t; s < 396; s += 256) fl[s] = 0.f;
  __syncthreads();                       // B1

  short* wxt = xt + wv*2816;             // this wave's [11][256] bf16 chunk

  // ---- STAGE (wave-private): 11 rows, contiguous 1KB wave-loads ----
#pragma unroll
  for (int n = 0; n < NN; ++n) {
    float4 v = *(const float4*)(streams + ((size_t)(n*RR + p))*DD + wv*256 + l*4);
    const int byte = (n*512 + l*8) ^ ((n & 7) << 4);
    *(uint2*)((char*)wxt + byte) = make_uint2(cvtpk(v.x, v.y), cvtpk(v.z, v.w));
  }

  // ---- MFMA (wave-private LDS reads; in-order DS pipe, no barrier) ----
  const int arow  = (lr < NN) ? lr : (NN-1);     // clamp pad rows (discarded)
  const int aswz  = (arow & 7) << 4;

  f32x4 acc0 = {0.f,0.f,0.f,0.f};        // dots j 0..15
  f32x4 acc1 = {0.f,0.f,0.f,0.f};        // dots j 16..21 + sum col 22
  f32x4 acc2 = {0.f,0.f,0.f,0.f};        // Gram (hss via w1'Gw1)
#pragma unroll
  for (int ksl = 0; ksl < 8; ++ksl) {
    const int byte = (arow*512 + ksl*64 + g*16) ^ aswz;
    short8 af = *(const short8*)((char*)wxt + byte);
    const size_t bo = (size_t)(wv*8 + ksl)*1024 + (size_t)l*8;
    short8 b0 = *(const short8*)(wfrag + bo);
    short8 b1 = *(const short8*)(wfrag + bo + 512);
    acc0 = __builtin_amdgcn_mfma_f32_16x16x32_bf16(af, b0, acc0, 0, 0, 0);
    acc1 = __builtin_amdgcn_mfma_f32_16x16x32_bf16(af, b1, acc1, 0, 0, 0);
    acc2 = __builtin_amdgcn_mfma_f32_16x16x32_bf16(af, af, acc2, 0, 0, 0);
  }

  // ---- accumulate partials via LDS atomics (ds_add_f32) ----
#pragma unroll
  for (int r = 0; r < 4; ++r) {
    const int row = g*4 + r;             // stream index n
    if (row < NN) {
      atomicAdd(&fl[row*36 + lr], acc0[r]);           // dots j 0..15
      if (lr <= 6)  atomicAdd(&fl[row*36 + 16 + lr], acc1[r]);  // j 16..22 (22=sum)
      if (lr < NN)  atomicAdd(&fl[row*36 + 24 + lr], acc2[r]);  // Gram cols
    }
  }
  __syncthreads();                       // B2

  // ---- single scalar phase: thread i<11 computes its full C row ----
  if (t < NN) {
    const int i = t;
    const float qgA = scal[2*i],      qbA = scal[2*i+1];
    const float qgM = scal[2*(NN+i)], qbM = scal[2*(NN+i)+1];

    float mu[NN], rs[NN];
#pragma unroll
    for (int n = 0; n < NN; ++n) {
      mu[n] = fl[n*36 + 22] * (1.f/DD);
      float vr = fl[n*36 + 24 + n] * (1.f/DD) - mu[n]*mu[n];
      rs[n] = rsqrtf(vr + EPSV);
    }

    float w1[NN], dM[NN];
    float mx = -3.0e38f;
#pragma unroll
    for (int n = 0; n < NN; ++n) {
      w1[n] = 0.f;
      if (n <= i) {
        float lg = (fl[n*36 + i] - mu[n]*qgA)*rs[n] + qbA;
        w1[n] = lg;
        mx = fmaxf(mx, lg);
      }
    }
    float S = 0.f;
#pragma unroll
    for (int n = 0; n < NN; ++n) if (n <= i) { float e = __expf(w1[n]-mx); w1[n] = e; S += e; }
    const float inv = 1.f/S;
    float muh = 0.f, hd = 0.f;
#pragma unroll
    for (int n = 0; n < NN; ++n) {
      if (n <= i) {
        w1[n] *= inv;
        dM[n] = fl[n*36 + 11 + i];
        muh += w1[n]*mu[n];
        hd  += w1[n]*dM[n];
      } else w1[n] = 0.f;
    }

    // hss = w1' G w1 via the MFMA Gram (zero-padded w1 -> branchless)
    float hss = 0.f;
#pragma unroll
    for (int m = 0; m < NN; ++m) {
      const float wm = w1[m];
      float acc = 0.f;
#pragma unroll
      for (int n = 0; n < NN; ++n) acc = fmaf(w1[n], fl[m*36 + 24 + n], acc);
      hss = fmaf(wm, acc, hss);
    }
    const float varh = hss*(1.f/DD) - muh*muh;
    const float rsh  = rsqrtf(varh + EPSV);
    const float lgh  = (hd - muh*qgM)*rsh + qbM;

    float lg2[NN], w2[NN];
    float mx2 = lgh;
#pragma unroll
    for (int n = 0; n < NN; ++n) if (n < i) {
      lg2[n] = (dM[n] - mu[n]*qgM)*rs[n] + qbM;
      mx2 = fmaxf(mx2, lg2[n]);
    }
    float eh = __expf(lgh - mx2);
    float S2 = eh;
#pragma unroll
    for (int n = 0; n < NN; ++n) if (n < i) { w2[n] = __expf(lg2[n]-mx2); S2 += w2[n]; }
    const float inv2 = 1.f/S2;
    const float ehw  = eh*inv2;
#pragma unroll
    for (int n = 0; n < NN; ++n) {
      float cc = ehw * w1[n];              // w1 zero-padded for n>i
      if (n < i) cc += w2[n]*inv2;
      Cs[i][n] = cc;
    }
  }
  __syncthreads();                       // B3

  // ---- combine: re-read own wave chunk (wave-private, no barrier needed),
  //      branchless over n, coalesced stores ----
  float xf[NN][4];
#pragma unroll
  for (int n = 0; n < NN; ++n) {
    const int byte = (n*512 + l*8) ^ ((n & 7) << 4);
    uint2 u = *(const uint2*)((char*)wxt + byte);
    xf[n][0] = b2f((unsigned short)(u.x & 0xFFFF));
    xf[n][1] = b2f((unsigned short)(u.x >> 16));
    xf[n][2] = b2f((unsigned short)(u.y & 0xFFFF));
    xf[n][3] = b2f((unsigned short)(u.y >> 16));
  }
  const int kt = wv*256 + l*4;           // == t*4
#pragma unroll
  for (int i = 0; i < NN; ++i) {
    float o0 = 0.f, o1 = 0.f, o2 = 0.f, o3 = 0.f;
#pragma unroll
    for (int n = 0; n < NN; ++n) {
      const float c = Cs[i][n];
      o0 = fmaf(c, xf[n][0], o0);
      o1 = fmaf(c, xf[n][1], o1);
      o2 = fmaf(c, xf[n][2], o2);
      o3 = fmaf(c, xf[n][3], o3);
    }
    *(float4*)(out + ((size_t)(i*RR + p))*DD + kt) = make_float4(o0, o1, o2, o3);
  }
}

extern "C" void kernel_launch(void* const* d_in, const int* in_sizes, int n_in,
                              void* d_out, int out_size, void* d_ws, size_t ws_size,
                              hipStream_t stream) {
  const float* streams = (const float*)d_in[0];
  const float* aq = (const float*)d_in[1];
  const float* ag = (const float*)d_in[2];
  const float* ab = (const float*)d_in[3];
  const float* mq = (const float*)d_in[4];
  const float* mg = (const float*)d_in[5];
  const float* mb = (const float*)d_in[6];
  float* outp = (float*)d_out;

  float* wsf   = (float*)d_ws;
  float* wvec  = wsf;
  float* scal  = wsf + OFF_SCAL;
  short* wfrag = (short*)(wsf + OFF_WFRAG);

  prep_kernel<<<dim3(2*NN), dim3(PREP_TPB), 0, stream>>>(aq, ag, ab, mq, mg, mb, wvec, scal);
  prep2_kernel<<<dim3(32), dim3(256), 0, stream>>>(wvec, wfrag);
  fused_kernel<<<dim3(RR), dim3(256), 0, stream>>>(streams, wfrag, scal, outp);
}

// Round 22
// 197.023 us; speedup vs baseline: 1.2282x; 1.2282x over previous
//
#include <hip/hip_runtime.h>
#include <math.h>

#define NN 11
#define RR 8192               // B*L positions
#define DD 1024
#define EPSV 1e-5f
#define PREP_TPB 256

// ---- ws layout (floats) ----
// wvec  : [22][1024] f32   @ 0
// scal  : [22][2]    f32   @ 22528 (padded to 64)
// wfrag : [32][2][64][8] bf16 @ 22592
#define OFF_SCAL 22528
#define OFF_WFRAG 22592

typedef __attribute__((ext_vector_type(8))) short short8;
typedef __attribute__((ext_vector_type(4))) float f32x4;

__device__ __forceinline__ float wave_reduce(float v) {
#pragma unroll
  for (int o = 32; o > 0; o >>= 1) v += __shfl_xor(v, o, 64);
  return v;
}

__device__ __forceinline__ unsigned cvtpk(float lo, float hi) {
  unsigned r;
  asm("v_cvt_pk_bf16_f32 %0, %1, %2" : "=v"(r) : "v"(lo), "v"(hi));
  return r;   // low16=bf16(lo), high16=bf16(hi); RTNE
}

__device__ __forceinline__ float b2f(unsigned short s) {
  return __uint_as_float(((unsigned)s) << 16);
}

__global__ __launch_bounds__(PREP_TPB) void prep_kernel(
    const float* __restrict__ aq, const float* __restrict__ ag, const float* __restrict__ ab,
    const float* __restrict__ mq, const float* __restrict__ mg, const float* __restrict__ mb,
    float* __restrict__ wvec, float* __restrict__ scal)
{
  const int j = blockIdx.x;              // 0..21
  const float *q, *g, *bt;
  if (j < NN) { q = aq + (size_t)j*DD;      g = ag + (size_t)j*DD;      bt = ab + (size_t)j*DD; }
  else        { q = mq + (size_t)(j-NN)*DD; g = mg + (size_t)(j-NN)*DD; bt = mb + (size_t)(j-NN)*DD; }
  const int t = threadIdx.x;
  float sqg = 0.f, sqb = 0.f;
  for (int d = t; d < DD; d += PREP_TPB) {
    float qq = q[d];
    float w  = qq * g[d];
    wvec[(size_t)j*DD + d] = w;
    sqg += w;
    sqb += qq * bt[d];
  }
  sqg = wave_reduce(sqg);
  sqb = wave_reduce(sqb);
  __shared__ float red[2][PREP_TPB/64];
  const int lane = t & 63, wid = t >> 6;
  if (lane == 0) { red[0][wid] = sqg; red[1][wid] = sqb; }
  __syncthreads();
  if (t == 0) {
    float a = 0.f, b2 = 0.f;
    for (int w = 0; w < PREP_TPB/64; ++w) { a += red[0][w]; b2 += red[1][w]; }
    scal[2*j]   = a;
    scal[2*j+1] = b2;
  }
}

// pack B fragments: wfrag[kstep][c][lane][e] = bf16(wvec[j][k]), j=c*16+(lane&15),
// k=kstep*32+(lane>>4)*8+e. j==22 -> 1.0 (row-sum rides the MFMA); other j>=22 -> 0.
__global__ __launch_bounds__(256) void prep2_kernel(
    const float* __restrict__ wvec, short* __restrict__ wfrag)
{
  const int kstep = blockIdx.x;          // 0..31
  const int t = threadIdx.x;
#pragma unroll
  for (int q = 0; q < 4; ++q) {
    const int idx  = t*4 + q;            // 0..1023
    const int c    = idx >> 9;
    const int lane = (idx >> 3) & 63;
    const int e    = idx & 7;
    const int k    = kstep*32 + (lane >> 4)*8 + e;
    const int j    = c*16 + (lane & 15);
    float v = (j < 22) ? wvec[(size_t)j*DD + k] : (j == 22 ? 1.0f : 0.f);
    unsigned u = __float_as_uint(v);
    u = (u + 0x7FFFu + ((u >> 16) & 1u)) >> 16;
    wfrag[(size_t)kstep*1024 + idx] = (short)u;
  }
}

// Fused: block = ONE position. R18 structure with the stage barrier REMOVED:
// thread t writes tile segment [wv*512,(wv+1)*512) of each row, and wave wv's
// MFMA ksteps [wv*8,wv*8+8) read exactly those bytes back -> dataflow is
// wave-private; the in-order DS pipe handles RAW. 3 barriers total.
__global__ __launch_bounds__(256) void fused_kernel(
    const float* __restrict__ streams, const short* __restrict__ wfrag,
    const float* __restrict__ scal, float* __restrict__ out)
{
  __shared__ __align__(16) short xt[NN*1024];    // 22528 B bf16 tile, swizzled
  __shared__ float fl4[4*11*40];                 // per-wave partials; reduced into [0]
  __shared__ float Cs[11][12];                   // final coeffs (zero-padded)

  const int p  = blockIdx.x;
  const int t  = threadIdx.x;
  const int l  = t & 63;
  const int wv = t >> 6;

  // ---- STAGE: 11 rows x 1024 f32 -> bf16 LDS; one float4/thread/row ----
#pragma unroll
  for (int n = 0; n < NN; ++n) {
    float4 v = *(const float4*)(streams + ((size_t)(n*RR + p))*DD + t*4);
    const int byte = (n*2048 + t*8) ^ ((n & 7) << 4);
    *(uint2*)((char*)xt + byte) = make_uint2(cvtpk(v.x, v.y), cvtpk(v.z, v.w));
  }
  // NO barrier: wave wv's MFMA reads only bytes it wrote (segment wv*512..)

  // ---- MFMA: wave wv handles ksteps [wv*8, wv*8+8) ----
  const int lr = l & 15, g = l >> 4;
  const int arow  = (lr < NN) ? lr : (NN-1);     // clamp pad rows (discarded)
  const int abase = arow*2048;
  const int aswz  = (arow & 7) << 4;

  f32x4 acc0 = {0.f,0.f,0.f,0.f};        // dots j 0..15
  f32x4 acc1 = {0.f,0.f,0.f,0.f};        // dots j 16..21 + sum col 22
  f32x4 acc2 = {0.f,0.f,0.f,0.f};        // Gram
#pragma unroll
  for (int ksl = 0; ksl < 8; ++ksl) {
    const int ks = wv*8 + ksl;
    const int byte = (abase + ks*64 + g*16) ^ aswz;
    short8 af = *(const short8*)((char*)xt + byte);
    const size_t bo = (size_t)ks*1024 + (size_t)l*8;
    short8 b0 = *(const short8*)(wfrag + bo);
    short8 b1 = *(const short8*)(wfrag + bo + 512);
    acc0 = __builtin_amdgcn_mfma_f32_16x16x32_bf16(af, b0, acc0, 0, 0, 0);
    acc1 = __builtin_amdgcn_mfma_f32_16x16x32_bf16(af, b1, acc1, 0, 0, 0);
    acc2 = __builtin_amdgcn_mfma_f32_16x16x32_bf16(af, af, acc2, 0, 0, 0);
  }
  // per-wave partial region [11][40]: 0..22 dots+sum, 24..34 Gram
  {
    float* R0 = fl4 + wv*440;
#pragma unroll
    for (int r = 0; r < 4; ++r) {
      const int row = g*4 + r;
      if (row < NN) {
        float* R = R0 + row*40;
        R[lr] = acc0[r];
        if (lr <= 6)  R[16 + lr] = acc1[r];
        if (lr < NN)  R[24 + lr] = acc2[r];
      }
    }
  }
  __syncthreads();                       // B1

  // ---- reduce the 4 wave partials into fl4[0] (440 entries) ----
  for (int s = t; s < 440; s += 256)
    fl4[s] = fl4[s] + fl4[440 + s] + fl4[880 + s] + fl4[1320 + s];
  __syncthreads();                       // B2

  // ---- single scalar phase: thread i<11 computes its full C row ----
  if (t < NN) {
    const int i = t;
    const float qgA = scal[2*i],      qbA = scal[2*i+1];
    const float qgM = scal[2*(NN+i)], qbM = scal[2*(NN+i)+1];

    float mu[NN], rs[NN];
#pragma unroll
    for (int n = 0; n < NN; ++n) {
      mu[n] = fl4[n*40 + 22] * (1.f/DD);
      float vr = fl4[n*40 + 24 + n] * (1.f/DD) - mu[n]*mu[n];
      rs[n] = rsqrtf(vr + EPSV);
    }

    float w1[NN], dM[NN];
    float mx = -3.0e38f;
#pragma unroll
    for (int n = 0; n < NN; ++n) {
      w1[n] = 0.f;
      if (n <= i) {
        float lg = (fl4[n*40 + i] - mu[n]*qgA)*rs[n] + qbA;
        w1[n] = lg;
        mx = fmaxf(mx, lg);
      }
    }
    float S = 0.f;
#pragma unroll
    for (int n = 0; n < NN; ++n) if (n <= i) { float e = __expf(w1[n]-mx); w1[n] = e; S += e; }
    const float inv = 1.f/S;
    float muh = 0.f, hd = 0.f;
#pragma unroll
    for (int n = 0; n < NN; ++n) {
      if (n <= i) {
        w1[n] *= inv;
        dM[n] = fl4[n*40 + 11 + i];
        muh += w1[n]*mu[n];
        hd  += w1[n]*dM[n];
      } else w1[n] = 0.f;
    }

    // hss = w1' G w1 via the MFMA Gram (zero-padded w1 -> branchless)
    float hss = 0.f;
#pragma unroll
    for (int m = 0; m < NN; ++m) {
      const float wm = w1[m];
      float acc = 0.f;
#pragma unroll
      for (int n = 0; n < NN; ++n) acc = fmaf(w1[n], fl4[m*40 + 24 + n], acc);
      hss = fmaf(wm, acc, hss);
    }
    const float varh = hss*(1.f/DD) - muh*muh;
    const float rsh  = rsqrtf(varh + EPSV);
    const float lgh  = (hd - muh*qgM)*rsh + qbM;

    float lg2[NN], w2[NN];
    float mx2 = lgh;
#pragma unroll
    for (int n = 0; n < NN; ++n) if (n < i) {
      lg2[n] = (dM[n] - mu[n]*qgM)*rs[n] + qbM;
      mx2 = fmaxf(mx2, lg2[n]);
    }
    float eh = __expf(lgh - mx2);
    float S2 = eh;
#pragma unroll
    for (int n = 0; n < NN; ++n) if (n < i) { w2[n] = __expf(lg2[n]-mx2); S2 += w2[n]; }
    const float inv2 = 1.f/S2;
    const float ehw  = eh*inv2;
#pragma unroll
    for (int n = 0; n < NN; ++n) {
      float cc = ehw * w1[n];              // w1 zero-padded for n>i
      if (n < i) cc += w2[n]*inv2;
      Cs[i][n] = cc;
    }
  }
  __syncthreads();                       // B3

  // ---- combine: thread owns 4 k's; branchless over n; coalesced stores ----
  const int kt = t*4;
  float xf[NN][4];
#pragma unroll
  for (int n = 0; n < NN; ++n) {
    const int byte = (n*2048 + kt*2) ^ ((n & 7) << 4);
    uint2 u = *(const uint2*)((char*)xt + byte);
    xf[n][0] = b2f((unsigned short)(u.x & 0xFFFF));
    xf[n][1] = b2f((unsigned short)(u.x >> 16));
    xf[n][2] = b2f((unsigned short)(u.y & 0xFFFF));
    xf[n][3] = b2f((unsigned short)(u.y >> 16));
  }
#pragma unroll
  for (int i = 0; i < NN; ++i) {
    float o0 = 0.f, o1 = 0.f, o2 = 0.f, o3 = 0.f;
#pragma unroll
    for (int n = 0; n < NN; ++n) {
      const float c = Cs[i][n];
      o0 = fmaf(c, xf[n][0], o0);
      o1 = fmaf(c, xf[n][1], o1);
      o2 = fmaf(c, xf[n][2], o2);
      o3 = fmaf(c, xf[n][3], o3);
    }
    *(float4*)(out + ((size_t)(i*RR + p))*DD + kt) = make_float4(o0, o1, o2, o3);
  }
}

extern "C" void kernel_launch(void* const* d_in, const int* in_sizes, int n_in,
                              void* d_out, int out_size, void* d_ws, size_t ws_size,
                              hipStream_t stream) {
  const float* streams = (const float*)d_in[0];
  const float* aq = (const float*)d_in[1];
  const float* ag = (const float*)d_in[2];
  const float* ab = (const float*)d_in[3];
  const float* mq = (const float*)d_in[4];
  const float* mg = (const float*)d_in[5];
  const float* mb = (const float*)d_in[6];
  float* outp = (float*)d_out;

  float* wsf   = (float*)d_ws;
  float* wvec  = wsf;
  float* scal  = wsf + OFF_SCAL;
  short* wfrag = (short*)(wsf + OFF_WFRAG);

  prep_kernel<<<dim3(2*NN), dim3(PREP_TPB), 0, stream>>>(aq, ag, ab, mq, mg, mb, wvec, scal);
  prep2_kernel<<<dim3(32), dim3(256), 0, stream>>>(wvec, wfrag);
  fused_kernel<<<dim3(RR), dim3(256), 0, stream>>>(streams, wfrag, scal, outp);
}